// Round 7
// baseline (337.566 us; speedup 1.0000x reference)
//
#include <hip/hip_runtime.h>

// VanillaRNN: S=512, I=1, H=256, C=10, B=2048, fp32 in/out.
// R7: conflict-free LDS. R6 measured 336 cyc/step of bank-conflict stalls
// (25% of step): with b128 ops, rows n and n+8 always alias the same 4-bank
// group (pigeonhole: 16 lanes/phase, 8 groups). Fix: 8-byte granules,
// granule L of row n stored at slot L^n (full 4-bit xor) -> every 16-lane
// phase of a b64 op covers all 16 bank-pairs exactly once. Reads: 16
// ds_read_b64/wave; operand = concat of two f16x4 (register naming only).
// Rest as R6: 128 blocks x 8 waves (2/SIMD TLP), 2 m-tiles/wave, C-operand
// carries b_h + W_hx*x_t, x prefetch, weights pre-scaled by 2*log2e,
// tanh = 1 - 2*rcp(exp2(s)+1). waves_per_eu(2,2): 256-VGPR budget, no spill.

#define SEQ   512
#define HID   256
#define NCLS  10
#define BN    16      // batch per block
#define NT    512     // 8 waves

typedef _Float16 f16x8 __attribute__((ext_vector_type(8)));
typedef _Float16 f16x4 __attribute__((ext_vector_type(4)));
typedef float    f32x4 __attribute__((ext_vector_type(4)));

__global__ __launch_bounds__(NT)
__attribute__((amdgpu_waves_per_eu(2, 2)))
void rnn_mfma(
    const float* __restrict__ x,     // [B, S]
    const float* __restrict__ W_hx,  // [H]
    const float* __restrict__ W_hh,  // [H, H]
    const float* __restrict__ W_ph,  // [C, H]
    const float* __restrict__ b_h,   // [H]
    const float* __restrict__ b_p,   // [C]
    float* __restrict__ out)         // [B, C]
{
    // hT[buf][n][.]: 8B-granule L of row n at physical granule L^n
    __shared__ __align__(16) _Float16 hT[2][BN][HID];    // 16 KB
    __shared__ __align__(16) float xs[SEQ + 2][BN];      // 32.9 KB

    const int tid  = threadIdx.x;
    const int lane = tid & 63;
    const int wave = tid >> 6;       // 0..7
    const int n16  = lane & 15;
    const int quad = lane >> 4;      // 0..3
    const int b0   = blockIdx.x * BN;

    const float SC = 2.885390081777926814f;   // 2*log2(e)

    // ---- A-frags: rows [wave*32, wave*32+32), pre-scaled by SC, f16 ----
    // A[m = n16][k = quad*8 + j]
    f16x8 afrag[2][8];
#pragma unroll
    for (int mt = 0; mt < 2; ++mt) {
        const int row = wave * 32 + mt * 16 + n16;
#pragma unroll
        for (int ks = 0; ks < 8; ++ks) {
            const float4* p = (const float4*)&W_hh[row * HID + ks * 32 + quad * 8];
            float4 u = p[0], v = p[1];
            f16x8 a;
            a[0] = (_Float16)(SC * u.x); a[1] = (_Float16)(SC * u.y);
            a[2] = (_Float16)(SC * u.z); a[3] = (_Float16)(SC * u.w);
            a[4] = (_Float16)(SC * v.x); a[5] = (_Float16)(SC * v.y);
            a[6] = (_Float16)(SC * v.z); a[7] = (_Float16)(SC * v.w);
            afrag[mt][ks] = a;
        }
    }
    // D rows for this lane: row = wave*32 + mt*16 + quad*4 + r
    f32x4 bias[2], wxv[2];
#pragma unroll
    for (int mt = 0; mt < 2; ++mt)
#pragma unroll
        for (int r = 0; r < 4; ++r) {
            const int row = wave * 32 + mt * 16 + quad * 4 + r;
            bias[mt][r] = SC * b_h[row];
            wxv[mt][r]  = SC * W_hx[row];
        }

    // ---- swizzled byte offsets ----
    // read (ks, par): logical granule L = 8ks + 2quad + par of row n16,
    //   at byte n16*512 + (L^n16)*8
    int roff[16];
#pragma unroll
    for (int ks = 0; ks < 8; ++ks)
#pragma unroll
        for (int par = 0; par < 2; ++par)
            roff[2 * ks + par] =
                n16 * 512 + (((8 * ks + 2 * quad + par) ^ n16) << 3);
    // write mt: rows (wave*32+mt*16+quad*4 ..+3) of col n16 =
    //   granule 8*wave+4*mt+quad of row n16
    int woff[2];
#pragma unroll
    for (int mt = 0; mt < 2; ++mt)
        woff[mt] = n16 * 512 + (((8 * wave + 4 * mt + quad) ^ n16) << 3);

    // ---- stage xs[t][n] = x[b0+n][t] ----
    for (int i = tid; i < BN * SEQ / 4; i += NT) {
        const int n = i >> 7, t4 = (i & 127) * 4;
        float4 v = *(const float4*)&x[(b0 + n) * SEQ + t4];
        xs[t4 + 0][n] = v.x; xs[t4 + 1][n] = v.y;
        xs[t4 + 2][n] = v.z; xs[t4 + 3][n] = v.w;
    }
    // ---- h0 = 0 (buffer 0 only; buffer 1 fully written each odd step) ----
    for (int i = tid; i < BN * HID / 2; i += NT) ((float*)hT[0])[i] = 0.0f;
    __syncthreads();

    float xv = xs[0][n16];   // prefetched x_t for step 0

#define RNN_STEP(T, RD, WR)                                                   \
    {                                                                         \
        const float xnxt = xs[(T) + 1][n16];  /* prefetch next step's x */    \
        const char* hb = (const char*)hT[RD];                                 \
        f16x4 bfr[16];                                                        \
        _Pragma("unroll")                                                     \
        for (int i = 0; i < 16; ++i)                                          \
            bfr[i] = *(const f16x4*)(hb + roff[i]);   /* ds_read_b64 */       \
        f32x4 acc[2];                                                         \
        _Pragma("unroll")                                                     \
        for (int mt = 0; mt < 2; ++mt) {                                      \
            f32x4 c0;                                                         \
            _Pragma("unroll")                                                 \
            for (int r = 0; r < 4; ++r)                                       \
                c0[r] = fmaf(wxv[mt][r], xv, bias[mt][r]);                    \
            f16x8 b = __builtin_shufflevector(bfr[0], bfr[1],                 \
                                              0, 1, 2, 3, 4, 5, 6, 7);        \
            acc[mt] = __builtin_amdgcn_mfma_f32_16x16x32_f16(                 \
                afrag[mt][0], b, c0, 0, 0, 0);                                \
        }                                                                     \
        _Pragma("unroll")                                                     \
        for (int ks = 1; ks < 8; ++ks) {                                      \
            f16x8 b = __builtin_shufflevector(bfr[2 * ks], bfr[2 * ks + 1],   \
                                              0, 1, 2, 3, 4, 5, 6, 7);        \
            _Pragma("unroll")                                                 \
            for (int mt = 0; mt < 2; ++mt)                                    \
                acc[mt] = __builtin_amdgcn_mfma_f32_16x16x32_f16(             \
                    afrag[mt][ks], b, acc[mt], 0, 0, 0);                      \
        }                                                                     \
        char* wb = (char*)hT[WR];                                             \
        _Pragma("unroll")                                                     \
        for (int mt = 0; mt < 2; ++mt) {                                      \
            f16x4 h4;                                                         \
            _Pragma("unroll")                                                 \
            for (int r = 0; r < 4; ++r) {                                     \
                float ex = __builtin_amdgcn_exp2f(acc[mt][r]);                \
                float rc = __builtin_amdgcn_rcpf(ex + 1.0f);                  \
                h4[r] = (_Float16)(1.0f - 2.0f * rc);                         \
            }                                                                 \
            *(f16x4*)(wb + woff[mt]) = h4;            /* ds_write_b64 */      \
        }                                                                     \
        xv = xnxt;                                                            \
        __syncthreads();                                                      \
    }

    for (int t = 0; t < SEQ; t += 2) {
        RNN_STEP(t, 0, 1);
        RNN_STEP(t + 1, 1, 0);
    }
#undef RNN_STEP

    // ---- output: out[b][c] = b_p[c] + sum_j W_ph[c][j] * h_final[j][b] ----
    // final h in hT[0]; logical f16 j of row b at ((j>>2)^b)*4 + (j&3)
    if (tid < BN * NCLS) {
        const int b = tid / NCLS, c = tid % NCLS;
        float sum = b_p[c];
        const _Float16* hp = hT[0][b];
        for (int j = 0; j < HID; ++j) {
            const int ph = ((((j >> 2) ^ b) << 2) | (j & 3));
            sum += W_ph[c * HID + j] * (float)hp[ph];
        }
        out[(b0 + b) * NCLS + c] = sum;
    }
}

extern "C" void kernel_launch(void* const* d_in, const int* in_sizes, int n_in,
                              void* d_out, int out_size, void* d_ws, size_t ws_size,
                              hipStream_t stream) {
    const float* x    = (const float*)d_in[0];
    const float* W_hx = (const float*)d_in[1];
    const float* W_hh = (const float*)d_in[2];
    const float* W_ph = (const float*)d_in[3];
    const float* b_h  = (const float*)d_in[4];
    const float* b_p  = (const float*)d_in[5];
    float* out = (float*)d_out;

    rnn_mfma<<<dim3(2048 / BN), dim3(NT), 0, stream>>>(
        x, W_hx, W_hh, W_ph, b_h, b_p, out);
}

// Round 8
// 331.868 us; speedup vs baseline: 1.0172x; 1.0172x over previous
//
#include <hip/hip_runtime.h>

// VanillaRNN: S=512, I=1, H=256, C=10, B=2048, fp32 in/out.
// R8: R6 structure + per-oct-injective LDS swizzle.
// R6/R7 lesson: LDS cost = insts x per-inst cycles, so b128 (8 insts/wave)
// strictly dominates b64 (16) -- IF conflict-free. Conflict invariant: within
// any 8-lane oct (fixed quad), the 8 row indices must hit 8 distinct
// bank-groups ("per-oct injective"); 2-way across octs is free (m136).
// Layout: 16B-granule G of batch-row n stored at slot16 = G ^ n (reads
// b128: G = 4ks+quad, ^n16 low bits spans all 8 groups per oct). Writes
// b64 granule gw = 8*wave+4*mt+quad at slot64 = gw ^ (n16<<1) -- the same
// mapping at 8B granularity (consistency verified element-wise).
// Rest as R6: 128 blocks x 8 waves (2/SIMD TLP), 2 m-tiles/wave, C-operand
// carries b_h + W_hx*x_t, x prefetch, weights pre-scaled by 2*log2e,
// tanh = 1 - 2*rcp(exp2(s)+1). waves_per_eu(2,2): no spill (R1/R2 lesson).

#define SEQ   512
#define HID   256
#define NCLS  10
#define BN    16      // batch per block
#define NT    512     // 8 waves

typedef _Float16 f16x8 __attribute__((ext_vector_type(8)));
typedef _Float16 f16x4 __attribute__((ext_vector_type(4)));
typedef float    f32x4 __attribute__((ext_vector_type(4)));

__global__ __launch_bounds__(NT)
__attribute__((amdgpu_waves_per_eu(2, 2)))
void rnn_mfma(
    const float* __restrict__ x,     // [B, S]
    const float* __restrict__ W_hx,  // [H]
    const float* __restrict__ W_hh,  // [H, H]
    const float* __restrict__ W_ph,  // [C, H]
    const float* __restrict__ b_h,   // [H]
    const float* __restrict__ b_p,   // [C]
    float* __restrict__ out)         // [B, C]
{
    // hT[buf][n][.]: 16B-granule G of batch-row n at physical slot G^n
    __shared__ __align__(16) _Float16 hT[2][BN][HID];    // 16 KB
    __shared__ __align__(16) float xs[SEQ + 2][BN];      // 32.9 KB

    const int tid  = threadIdx.x;
    const int lane = tid & 63;
    const int wave = tid >> 6;       // 0..7
    const int n16  = lane & 15;
    const int quad = lane >> 4;      // 0..3
    const int b0   = blockIdx.x * BN;

    const float SC = 2.885390081777926814f;   // 2*log2(e)

    // ---- A-frags: rows [wave*32, wave*32+32), pre-scaled by SC, f16 ----
    // A[m = n16][k = quad*8 + j]
    f16x8 afrag[2][8];
#pragma unroll
    for (int mt = 0; mt < 2; ++mt) {
        const int row = wave * 32 + mt * 16 + n16;
#pragma unroll
        for (int ks = 0; ks < 8; ++ks) {
            const float4* p = (const float4*)&W_hh[row * HID + ks * 32 + quad * 8];
            float4 u = p[0], v = p[1];
            f16x8 a;
            a[0] = (_Float16)(SC * u.x); a[1] = (_Float16)(SC * u.y);
            a[2] = (_Float16)(SC * u.z); a[3] = (_Float16)(SC * u.w);
            a[4] = (_Float16)(SC * v.x); a[5] = (_Float16)(SC * v.y);
            a[6] = (_Float16)(SC * v.z); a[7] = (_Float16)(SC * v.w);
            afrag[mt][ks] = a;
        }
    }
    // D rows for this lane: row = wave*32 + mt*16 + quad*4 + r
    f32x4 bias[2], wxv[2];
#pragma unroll
    for (int mt = 0; mt < 2; ++mt)
#pragma unroll
        for (int r = 0; r < 4; ++r) {
            const int row = wave * 32 + mt * 16 + quad * 4 + r;
            bias[mt][r] = SC * b_h[row];
            wxv[mt][r]  = SC * W_hx[row];
        }

    // ---- swizzled byte offsets ----
    // read ks (b128): granule16 G = 4ks+quad of row n16 at slot16 = G^n16
    int roff[8];
#pragma unroll
    for (int ks = 0; ks < 8; ++ks)
        roff[ks] = n16 * 512 + (((4 * ks + quad) ^ n16) << 4);
    // write mt (b64): granule64 gw = 8*wave+4*mt+quad (rows base/4) of row
    // n16 at slot64 = gw ^ (n16<<1)  (== slot16 mapping at 8B granularity)
    int woff[2];
#pragma unroll
    for (int mt = 0; mt < 2; ++mt)
        woff[mt] = n16 * 512 + (((8 * wave + 4 * mt + quad) ^ (n16 << 1)) << 3);

    // ---- stage xs[t][n] = x[b0+n][t] ----
    for (int i = tid; i < BN * SEQ / 4; i += NT) {
        const int n = i >> 7, t4 = (i & 127) * 4;
        float4 v = *(const float4*)&x[(b0 + n) * SEQ + t4];
        xs[t4 + 0][n] = v.x; xs[t4 + 1][n] = v.y;
        xs[t4 + 2][n] = v.z; xs[t4 + 3][n] = v.w;
    }
    // ---- h0 = 0 (buffer 0 only; buffer 1 fully written each odd step) ----
    for (int i = tid; i < BN * HID / 2; i += NT) ((float*)hT[0])[i] = 0.0f;
    __syncthreads();

    float xv = xs[0][n16];   // prefetched x_t for step 0

#define RNN_STEP(T, RD, WR)                                                   \
    {                                                                         \
        const float xnxt = xs[(T) + 1][n16];  /* prefetch next step's x */    \
        const char* hb = (const char*)hT[RD];                                 \
        f16x8 bfr[8];                                                         \
        _Pragma("unroll")                                                     \
        for (int ks = 0; ks < 8; ++ks)                                        \
            bfr[ks] = *(const f16x8*)(hb + roff[ks]);  /* ds_read_b128 */     \
        f32x4 acc[2];                                                         \
        _Pragma("unroll")                                                     \
        for (int mt = 0; mt < 2; ++mt) {                                      \
            f32x4 c0;                                                         \
            _Pragma("unroll")                                                 \
            for (int r = 0; r < 4; ++r)                                       \
                c0[r] = fmaf(wxv[mt][r], xv, bias[mt][r]);                    \
            acc[mt] = __builtin_amdgcn_mfma_f32_16x16x32_f16(                 \
                afrag[mt][0], bfr[0], c0, 0, 0, 0);                           \
        }                                                                     \
        _Pragma("unroll")                                                     \
        for (int ks = 1; ks < 8; ++ks)                                        \
            _Pragma("unroll")                                                 \
            for (int mt = 0; mt < 2; ++mt)                                    \
                acc[mt] = __builtin_amdgcn_mfma_f32_16x16x32_f16(             \
                    afrag[mt][ks], bfr[ks], acc[mt], 0, 0, 0);                \
        char* wb = (char*)hT[WR];                                             \
        _Pragma("unroll")                                                     \
        for (int mt = 0; mt < 2; ++mt) {                                      \
            f16x4 h4;                                                         \
            _Pragma("unroll")                                                 \
            for (int r = 0; r < 4; ++r) {                                     \
                float ex = __builtin_amdgcn_exp2f(acc[mt][r]);                \
                float rc = __builtin_amdgcn_rcpf(ex + 1.0f);                  \
                h4[r] = (_Float16)(1.0f - 2.0f * rc);                         \
            }                                                                 \
            *(f16x4*)(wb + woff[mt]) = h4;            /* ds_write_b64 */      \
        }                                                                     \
        xv = xnxt;                                                            \
        __syncthreads();                                                      \
    }

    for (int t = 0; t < SEQ; t += 2) {
        RNN_STEP(t, 0, 1);
        RNN_STEP(t + 1, 1, 0);
    }
#undef RNN_STEP

    // ---- output: out[b][c] = b_p[c] + sum_j W_ph[c][j] * h_final[j][b] ----
    // final h in hT[0]; f16 j of row b at ((j>>2)^(2b))*4 + (j&3)
    if (tid < BN * NCLS) {
        const int b = tid / NCLS, c = tid % NCLS;
        float sum = b_p[c];
        const _Float16* hp = hT[0][b];
        for (int j = 0; j < HID; ++j) {
            const int ph = ((((j >> 2) ^ (2 * b)) << 2) | (j & 3));
            sum += W_ph[c * HID + j] * (float)hp[ph];
        }
        out[(b0 + b) * NCLS + c] = sum;
    }
}

extern "C" void kernel_launch(void* const* d_in, const int* in_sizes, int n_in,
                              void* d_out, int out_size, void* d_ws, size_t ws_size,
                              hipStream_t stream) {
    const float* x    = (const float*)d_in[0];
    const float* W_hx = (const float*)d_in[1];
    const float* W_hh = (const float*)d_in[2];
    const float* W_ph = (const float*)d_in[3];
    const float* b_h  = (const float*)d_in[4];
    const float* b_p  = (const float*)d_in[5];
    float* out = (float*)d_out;

    rnn_mfma<<<dim3(2048 / BN), dim3(NT), 0, stream>>>(
        x, W_hx, W_hh, W_ph, b_h, b_p, out);
}